// Round 9
// baseline (14.922 us; speedup 1.0000x reference)
//
#include <hip/hip_runtime.h>

#define NUM_Z 100
#define NUM_G 512
#define DIM   64
#define THREADS 1024
#define CHUNK 128            // nodes per pass; feat tile = 32 KB LDS

// Wave-cooperative 64-ary lower_bound: first i with arr[i] >= target.
__device__ __forceinline__ int lower_bound_wave(const int* __restrict__ arr, int n,
                                                int target, int lane) {
    int lo = 0, len = n;
    while (len > 0) {
        int step = (len + 63) >> 6;
        int idx  = lo + lane * step;
        int v    = (idx < n) ? arr[idx] : 0x7fffffff;
        unsigned long long m = __ballot(v < target);
        int k = (int)__popcll(m);
        if (k == 0) break;
        int rem = k * step; if (rem > len) rem = len;
        int hi  = lo + rem;
        lo += (k - 1) * step + 1;
        len = hi - lo;
    }
    return lo;
}

// One block per graph, NO sort. Stage feat rows (node order, coalesced,
// issued early) + z values into LDS; one barrier; then each 16-lane group
// scans the z list from LDS (broadcast int4 reads) and pulls its two bins'
// matches from the LDS tile (~12 cyc each). One barrier per chunk.
__global__ __launch_bounds__(THREADS) void anp_scan2_kernel(
    const float4* __restrict__ feat,   // [N*16] quads of [N,64] features
    const int*    __restrict__ z,      // [N] in [1,100]
    const int*    __restrict__ batch,  // [N] sorted graph ids
    float*        __restrict__ pooled, // [G, 100*64]
    int n)
{
    __shared__ float4 tile[CHUNK * 16];   // 32 KB node-ordered feature rows
    __shared__ int    zs[CHUNK];          // z-1 per staged node (-1 pad)
    __shared__ int    sb[2];

    const int g    = blockIdx.x;
    const int tid  = threadIdx.x;
    const int wave = tid >> 6;
    const int lane = tid & 63;
    const int grp  = tid >> 4;            // 0..63; gather groups 0..49 active
    const int q    = tid & 15;            // float4 quad within the 64-dim row

    if (wave < 2) {
        int r = lower_bound_wave(batch, n, g + wave, lane);
        if (lane == 0) sb[wave] = r;
    }
    __syncthreads();                      // B1
    const int start = sb[0];
    const int end   = sb[1];
    const int cnt   = end - start;

    float4 a0 = make_float4(0.f, 0.f, 0.f, 0.f);
    float4 a1 = make_float4(0.f, 0.f, 0.f, 0.f);
    const int jrow = tid >> 4;            // rows this thread stages (jrow, jrow+64)

    for (int cs = start; cs < end; cs += CHUNK) {
        const int m = min(CHUNK, end - cs);

        // issue all staging loads first (feat + z), write LDS after
        float4 s0, s1;
        const bool h0 = (jrow      < m);
        const bool h1 = (jrow + 64 < m);
        if (h0) s0 = feat[(size_t)(cs + jrow)      * 16 + q];
        if (h1) s1 = feat[(size_t)(cs + jrow + 64) * 16 + q];
        int zv = -1;
        if (tid < m) zv = z[cs + tid] - 1;

        if (tid < CHUNK) zs[tid] = zv;    // -1 pad: matches no group
        if (h0) tile[jrow * 16 + q]        = s0;
        if (h1) tile[(jrow + 64) * 16 + q] = s1;
        __syncthreads();                  // B2 (the only per-chunk barrier)

        // scan z list from LDS; pull matches from tile
        if (grp < 50) {
            const int4* zs4 = (const int4*)zs;
            const int m4 = (m + 3) >> 2;
            #pragma unroll 4
            for (int t = 0; t < m4; ++t) {
                int4 zq = zs4[t];         // full-wave LDS broadcast
                const int nb = t * 4;
                #define ANP_PROC(comp, off)                                      \
                    { const int zb = (comp);                                     \
                      if ((zb >> 1) == grp) {                                    \
                          const float pm = (float)(zb & 1);                      \
                          const float m0 = 1.0f - pm;                            \
                          float4 v = tile[(nb + (off)) * 16 + q];                \
                          a0.x = fmaf(v.x, m0, a0.x); a0.y = fmaf(v.y, m0, a0.y);\
                          a0.z = fmaf(v.z, m0, a0.z); a0.w = fmaf(v.w, m0, a0.w);\
                          a1.x = fmaf(v.x, pm, a1.x); a1.y = fmaf(v.y, pm, a1.y);\
                          a1.z = fmaf(v.z, pm, a1.z); a1.w = fmaf(v.w, pm, a1.w);\
                      } }
                ANP_PROC(zq.x, 0) ANP_PROC(zq.y, 1) ANP_PROC(zq.z, 2) ANP_PROC(zq.w, 3)
                #undef ANP_PROC
            }
        }
        if (cs + CHUNK < end) __syncthreads();   // tile/zs reuse guard only
    }

    if (grp < 50) {
        const float s = 1.0f / (float)(cnt > 1 ? cnt : 1);
        const int b0 = 2 * grp;
        float4* outv = (float4*)(pooled + (size_t)g * (NUM_Z * DIM));
        outv[(b0 + 0) * 16 + q] = make_float4(a0.x*s, a0.y*s, a0.z*s, a0.w*s);
        outv[(b0 + 1) * 16 + q] = make_float4(a1.x*s, a1.y*s, a1.z*s, a1.w*s);
    }
}

extern "C" void kernel_launch(void* const* d_in, const int* in_sizes, int n_in,
                              void* d_out, int out_size, void* d_ws, size_t ws_size,
                              hipStream_t stream) {
    const float* feat  = (const float*)d_in[0];
    const int*   z     = (const int*)d_in[1];
    const int*   batch = (const int*)d_in[2];
    float* pooled = (float*)d_out;
    const int n = in_sizes[0] / DIM;   // 50000

    anp_scan2_kernel<<<NUM_G, THREADS, 0, stream>>>(
        (const float4*)feat, z, batch, pooled, n);
}

// Round 10
// 11.296 us; speedup vs baseline: 1.3210x; 1.3210x over previous
//
#include <hip/hip_runtime.h>

#define NUM_Z 100
#define NUM_G 512
#define DIM   64
#define THREADS 1024
#define CHUNK 128            // nodes per pass; feat tile = 32 KB LDS

// Wave-cooperative 64-ary lower_bound: first i with arr[i] >= target.
__device__ __forceinline__ int lower_bound_wave(const int* __restrict__ arr, int n,
                                                int target, int lane) {
    int lo = 0, len = n;
    while (len > 0) {
        int step = (len + 63) >> 6;
        int idx  = lo + lane * step;
        int v    = (idx < n) ? arr[idx] : 0x7fffffff;
        unsigned long long m = __ballot(v < target);
        int k = (int)__popcll(m);
        if (k == 0) break;
        int rem = k * step; if (rem > len) rem = len;
        int hi  = lo + rem;
        lo += (k - 1) * step + 1;
        len = hi - lo;
    }
    return lo;
}

// One block per graph. Feature rows staged to LDS in node order (balanced,
// coalesced, issued early so HBM latency hides under the z counting-sort);
// bin-owner groups then gather from LDS where imbalance is ~free.
__global__ __launch_bounds__(THREADS) void anp_stage_kernel(
    const float4* __restrict__ feat,   // [N*16] quads of [N,64] features
    const int*    __restrict__ z,      // [N] in [1,100]
    const int*    __restrict__ batch,  // [N] sorted graph ids
    float*        __restrict__ pooled, // [G, 100*64]
    int n)
{
    __shared__ float4 tile[CHUNK * 16];       // 32 KB: node-ordered feature rows
    __shared__ int hist[128];
    __shared__ int scan_tmp[128];
    __shared__ int pref[NUM_Z + 1];
    __shared__ int cursor[NUM_Z];
    __shared__ unsigned short idx_sorted[CHUNK];  // chunk-local idx | parity<<15
    __shared__ int sb[2];
    __shared__ int wtot;

    const int g    = blockIdx.x;
    const int tid  = threadIdx.x;
    const int wave = tid >> 6;
    const int lane = tid & 63;
    const int grp  = tid >> 4;           // 0..63; gather groups 0..49 active
    const int q    = tid & 15;           // float4 quad within the 64-dim row
    const int b0   = 2 * grp;

    if (tid < 128) hist[tid] = 0;        // hoisted under the search
    if (wave < 2) {
        int r = lower_bound_wave(batch, n, g + wave, lane);
        if (lane == 0) sb[wave] = r;
    }
    __syncthreads();
    const int start = sb[0];
    const int end   = sb[1];
    const int cnt   = end - start;

    float4 a0 = make_float4(0.f, 0.f, 0.f, 0.f);
    float4 a1 = make_float4(0.f, 0.f, 0.f, 0.f);

    const int jrow = tid >> 4;           // row this thread stages (0..63, +64)

    for (int cs = start; cs < end; cs += CHUNK) {
        const int m = min(CHUNK, end - cs);

        // ---- issue staging loads EARLY (independent of the sort chain) ----
        float4 s0, s1;
        const bool h0 = (jrow      < m);
        const bool h1 = (jrow + 64 < m);
        if (h0) s0 = feat[(size_t)(cs + jrow)      * 16 + q];
        if (h1) s1 = feat[(size_t)(cs + jrow + 64) * 16 + q];

        int zv = 0;
        if (tid < m) {
            zv = z[cs + tid] - 1;        // coalesced
            atomicAdd(&hist[zv], 1);
        }
        __syncthreads();

        if (wave < 2) {                  // 128-entry shfl inclusive scan
            int e = hist[(wave << 6) + lane];
            #pragma unroll
            for (int d = 1; d < 64; d <<= 1) {
                int t = __shfl_up(e, d, 64);
                if (lane >= d) e += t;
            }
            scan_tmp[(wave << 6) + lane] = e;
            if (wave == 0 && lane == 63) wtot = e;
        }
        __syncthreads();

        if (tid <= NUM_Z) {
            int v = (tid == 0) ? 0
                  : scan_tmp[tid - 1] + ((tid - 1) >= 64 ? wtot : 0);
            pref[tid] = v;
            if (tid < NUM_Z) cursor[tid] = v;
        }
        __syncthreads();

        // ---- late LDS write of the staged rows (loads were in flight) ----
        if (h0) tile[jrow * 16 + q]        = s0;
        if (h1) tile[(jrow + 64) * 16 + q] = s1;
        if (tid < m) {
            int p = atomicAdd(&cursor[zv], 1);
            idx_sorted[p] = (unsigned short)(tid | ((zv & 1) << 15));
        }
        __syncthreads();

        // ---- gather from LDS: imbalance now costs ~12 cyc/node, not ~900 ----
        if (grp < 50) {
            const int off = pref[b0];
            const int c   = pref[b0 + 2] - off;
            for (int base = 0; base < c; base += 16) {
                const int nb = min(16, c - base);
                int myraw = (q < nb) ? (int)idx_sorted[off + base + q] : 0;
                #pragma unroll 4
                for (int j = 0; j < nb; ++j) {
                    int raw  = __shfl(myraw, ((lane >> 4) << 4) + j, 64);
                    int nd   = raw & 0x7fff;
                    float pm = (float)(raw >> 15);     // 0 -> b0, 1 -> b0+1
                    float4 v = tile[nd * 16 + q];      // ds_read_b128, 2-way=free
                    float m0 = 1.0f - pm;
                    a0.x = fmaf(v.x, m0, a0.x); a0.y = fmaf(v.y, m0, a0.y);
                    a0.z = fmaf(v.z, m0, a0.z); a0.w = fmaf(v.w, m0, a0.w);
                    a1.x = fmaf(v.x, pm, a1.x); a1.y = fmaf(v.y, pm, a1.y);
                    a1.z = fmaf(v.z, pm, a1.z); a1.w = fmaf(v.w, pm, a1.w);
                }
            }
        }
        if (cs + CHUNK < end) {          // multi-chunk only: recycle LDS
            __syncthreads();
            if (tid < 128) hist[tid] = 0;
            __syncthreads();
        }
    }

    if (grp < 50) {
        const float s = 1.0f / (float)(cnt > 1 ? cnt : 1);
        float4* outv = (float4*)(pooled + (size_t)g * (NUM_Z * DIM));
        outv[(b0 + 0) * 16 + q] = make_float4(a0.x*s, a0.y*s, a0.z*s, a0.w*s);
        outv[(b0 + 1) * 16 + q] = make_float4(a1.x*s, a1.y*s, a1.z*s, a1.w*s);
    }
}

extern "C" void kernel_launch(void* const* d_in, const int* in_sizes, int n_in,
                              void* d_out, int out_size, void* d_ws, size_t ws_size,
                              hipStream_t stream) {
    const float* feat  = (const float*)d_in[0];
    const int*   z     = (const int*)d_in[1];
    const int*   batch = (const int*)d_in[2];
    float* pooled = (float*)d_out;
    const int n = in_sizes[0] / DIM;   // 50000

    anp_stage_kernel<<<NUM_G, THREADS, 0, stream>>>(
        (const float4*)feat, z, batch, pooled, n);
}